// Round 1
// baseline (13174.954 us; speedup 1.0000x reference)
//
#include <hip/hip_runtime.h>
#include <math.h>

#define Bn 16
#define Sn 577
#define Dn 1024
#define Hn 16
#define DHn 64
#define Fn 4096
#define NROW (Bn*Sn)   // 9232
#define EPSf 1e-6f

// ---------------- LayerNorm: one block per row, 256 threads ----------------
__global__ __launch_bounds__(256) void ln_kernel(const float* __restrict__ x,
                                                 const float* __restrict__ g,
                                                 const float* __restrict__ b,
                                                 float* __restrict__ out) {
    int row = blockIdx.x;
    int tid = threadIdx.x;
    const float* xr = x + (size_t)row * Dn;
    float v[4];
    float s = 0.f;
#pragma unroll
    for (int i = 0; i < 4; i++) { v[i] = xr[tid + i * 256]; s += v[i]; }
    __shared__ float red[256];
    red[tid] = s; __syncthreads();
    for (int o = 128; o > 0; o >>= 1) { if (tid < o) red[tid] += red[tid + o]; __syncthreads(); }
    float mean = red[0] * (1.f / Dn);
    __syncthreads();
    float sq = 0.f;
#pragma unroll
    for (int i = 0; i < 4; i++) { float d = v[i] - mean; sq += d * d; }
    red[tid] = sq; __syncthreads();
    for (int o = 128; o > 0; o >>= 1) { if (tid < o) red[tid] += red[tid + o]; __syncthreads(); }
    float rstd = rsqrtf(red[0] * (1.f / Dn) + EPSf);
    float* orow = out + (size_t)row * Dn;
#pragma unroll
    for (int i = 0; i < 4; i++) {
        int c = tid + i * 256;
        orow[c] = (v[i] - mean) * rstd * g[c] + b[c];
    }
}

// ---------------- fp32 tiled GEMM: C = A[MxK] @ W[KxN] + bias, epilogue ----
// EPI: 0 = none, 1 = exact GELU, 2 = residual add
template<int EPI>
__global__ __launch_bounds__(256) void gemm_kernel(const float* __restrict__ A,
                                                   const float* __restrict__ W,
                                                   const float* __restrict__ bias,
                                                   const float* __restrict__ resid,
                                                   float* __restrict__ C,
                                                   int M, int N, int K) {
    const int BM = 64, BN = 64, BK = 16;
    __shared__ float As[BK][BM + 1];
    __shared__ float Ws[BK][BN];
    int tx = threadIdx.x, ty = threadIdx.y;
    int tid = ty * 16 + tx;
    int row0 = blockIdx.y * BM, col0 = blockIdx.x * BN;
    float acc[4][4] = {};
    for (int k0 = 0; k0 < K; k0 += BK) {
#pragma unroll
        for (int i = 0; i < 4; i++) {          // A tile 64x16
            int idx = i * 256 + tid;
            int ar = idx >> 4, ac = idx & 15;
            int grow = row0 + ar;
            As[ac][ar] = (grow < M) ? A[(size_t)grow * K + k0 + ac] : 0.f;
        }
#pragma unroll
        for (int i = 0; i < 4; i++) {          // W tile 16x64
            int idx = i * 256 + tid;
            int wr = idx >> 6, wc = idx & 63;
            Ws[wr][wc] = W[(size_t)(k0 + wr) * N + col0 + wc];
        }
        __syncthreads();
#pragma unroll
        for (int kk = 0; kk < BK; kk++) {
            float a[4], w[4];
#pragma unroll
            for (int i = 0; i < 4; i++) a[i] = As[kk][ty * 4 + i];
#pragma unroll
            for (int j = 0; j < 4; j++) w[j] = Ws[kk][tx * 4 + j];
#pragma unroll
            for (int i = 0; i < 4; i++)
#pragma unroll
                for (int j = 0; j < 4; j++)
                    acc[i][j] += a[i] * w[j];
        }
        __syncthreads();
    }
#pragma unroll
    for (int i = 0; i < 4; i++) {
        int grow = row0 + ty * 4 + i;
        if (grow >= M) continue;
#pragma unroll
        for (int j = 0; j < 4; j++) {
            int gcol = col0 + tx * 4 + j;
            float r = acc[i][j] + bias[gcol];
            if (EPI == 1) r = 0.5f * r * (1.f + erff(r * 0.70710678118654752f));
            if (EPI == 2) r += resid[(size_t)grow * N + gcol];
            C[(size_t)grow * N + gcol] = r;
        }
    }
}

// ---------------- attention: one block per (q_idx, b*h), 256 threads ------
__global__ __launch_bounds__(256) void attn_kernel(const float* __restrict__ Q,
                                                   const float* __restrict__ K,
                                                   const float* __restrict__ V,
                                                   float* __restrict__ O) {
    int qi = blockIdx.x;          // 0..S-1
    int bh = blockIdx.y;          // 0..B*H-1
    int b = bh >> 4;
    int h = bh & 15;
    int tid = threadIdx.x;        // 0..255
    size_t base = ((size_t)b * Sn) * Dn + (size_t)h * DHn;  // + s*Dn later

    __shared__ float q_lds[DHn];
    __shared__ float scores[640];
    __shared__ float Ktile[64][DHn + 1];
    __shared__ float red[256];
    __shared__ float pvred[4][DHn];

    if (tid < DHn) q_lds[tid] = Q[base + (size_t)qi * Dn + tid];
    __syncthreads();

    // scores = q . K / 8
    for (int kb = 0; kb < Sn; kb += 64) {
        int rows = min(64, Sn - kb);
#pragma unroll
        for (int i = 0; i < 16; i++) {
            int idx = i * 256 + tid;
            int r = idx >> 6, c = idx & 63;
            if (r < rows) Ktile[r][c] = K[base + (size_t)(kb + r) * Dn + c];
        }
        __syncthreads();
        int kr = tid >> 2, part = tid & 3;
        if (kr < rows) {
            float s = 0.f;
            int d0 = part * 16;
#pragma unroll
            for (int d = 0; d < 16; d++) s += q_lds[d0 + d] * Ktile[kr][d0 + d];
            s += __shfl_xor(s, 1);
            s += __shfl_xor(s, 2);
            if (part == 0) scores[kb + kr] = s * 0.125f;
        }
        __syncthreads();
    }

    // softmax over S
    float m = -1e30f;
    for (int i = tid; i < Sn; i += 256) m = fmaxf(m, scores[i]);
    red[tid] = m; __syncthreads();
    for (int o = 128; o > 0; o >>= 1) { if (tid < o) red[tid] = fmaxf(red[tid], red[tid + o]); __syncthreads(); }
    m = red[0]; __syncthreads();
    float ssum = 0.f;
    for (int i = tid; i < Sn; i += 256) { float e = __expf(scores[i] - m); scores[i] = e; ssum += e; }
    red[tid] = ssum; __syncthreads();
    for (int o = 128; o > 0; o >>= 1) { if (tid < o) red[tid] += red[tid + o]; __syncthreads(); }
    float inv = 1.f / red[0];
    __syncthreads();

    // ctx = probs @ V
    int d = tid & 63, kp = tid >> 6;   // 4 k-stripes
    float acc = 0.f;
    for (int k = kp; k < Sn; k += 4)
        acc += scores[k] * V[base + (size_t)k * Dn + d];
    pvred[kp][d] = acc;
    __syncthreads();
    if (tid < DHn) {
        float t = (pvred[0][tid] + pvred[1][tid] + pvred[2][tid] + pvred[3][tid]) * inv;
        O[base + (size_t)qi * Dn + tid] = t;
    }
}

extern "C" void kernel_launch(void* const* d_in, const int* in_sizes, int n_in,
                              void* d_out, int out_size, void* d_ws, size_t ws_size,
                              hipStream_t stream) {
    const float* x    = (const float*)d_in[0];
    const float* ln1g = (const float*)d_in[1];
    const float* ln1b = (const float*)d_in[2];
    const float* wq   = (const float*)d_in[3];
    const float* bq   = (const float*)d_in[4];
    const float* wk   = (const float*)d_in[5];
    const float* bk   = (const float*)d_in[6];
    const float* wv   = (const float*)d_in[7];
    const float* bv   = (const float*)d_in[8];
    const float* wo   = (const float*)d_in[9];
    const float* bo   = (const float*)d_in[10];
    const float* ln2g = (const float*)d_in[11];
    const float* ln2b = (const float*)d_in[12];
    const float* w1   = (const float*)d_in[13];
    const float* b1   = (const float*)d_in[14];
    const float* w2   = (const float*)d_in[15];
    const float* b2   = (const float*)d_in[16];
    float* out = (float*)d_out;

    const size_t SZ_ROWD = (size_t)NROW * Dn * sizeof(float);   // 37,814,272
    char* ws = (char*)d_ws;
    float* qbuf  = (float*)(ws);                    // [0, 37.8MB)
    float* kbuf  = (float*)(ws + SZ_ROWD);          // [37.8, 75.6)
    float* vbuf  = (float*)(ws + 2 * SZ_ROWD);      // [75.6, 113.4)
    float* hmid  = (float*)(ws);                    // [0, 151.3) reuses q/k/v
    float* xnbuf = (float*)(ws + 4 * SZ_ROWD);      // [151.3, 189.1)  (xn, then xn2)
    float* ctx   = (float*)(ws + 5 * SZ_ROWD);      // [189.1, 226.9)
    float* x1    = (float*)(ws + 6 * SZ_ROWD);      // [226.9, 264.7)

    dim3 blk2(16, 16);
    dim3 gD(Dn / 64, (NROW + 63) / 64);
    dim3 gF(Fn / 64, (NROW + 63) / 64);

    // attention sublayer
    ln_kernel<<<NROW, 256, 0, stream>>>(x, ln1g, ln1b, xnbuf);
    gemm_kernel<0><<<gD, blk2, 0, stream>>>(xnbuf, wq, bq, nullptr, qbuf, NROW, Dn, Dn);
    gemm_kernel<0><<<gD, blk2, 0, stream>>>(xnbuf, wk, bk, nullptr, kbuf, NROW, Dn, Dn);
    gemm_kernel<0><<<gD, blk2, 0, stream>>>(xnbuf, wv, bv, nullptr, vbuf, NROW, Dn, Dn);
    attn_kernel<<<dim3(Sn, Bn * Hn), 256, 0, stream>>>(qbuf, kbuf, vbuf, ctx);
    gemm_kernel<2><<<gD, blk2, 0, stream>>>(ctx, wo, bo, x, x1, NROW, Dn, Dn);
    // MLP sublayer
    ln_kernel<<<NROW, 256, 0, stream>>>(x1, ln2g, ln2b, xnbuf);
    gemm_kernel<1><<<gF, blk2, 0, stream>>>(xnbuf, w1, b1, nullptr, hmid, NROW, Fn, Dn);
    gemm_kernel<2><<<gD, blk2, 0, stream>>>(hmid, w2, b2, x1, out, NROW, Dn, Fn);
}

// Round 2
// 4178.048 us; speedup vs baseline: 3.1534x; 3.1534x over previous
//
#include <hip/hip_runtime.h>
#include <math.h>

#define Bn 16
#define Sn 577
#define Dn 1024
#define Hn 16
#define DHn 64
#define Fn 4096
#define NROW (Bn*Sn)   // 9232
#define EPSf 1e-6f

// ---------------- LayerNorm: one block per row, 256 threads ----------------
__global__ __launch_bounds__(256) void ln_kernel(const float* __restrict__ x,
                                                 const float* __restrict__ g,
                                                 const float* __restrict__ b,
                                                 float* __restrict__ out) {
    int row = blockIdx.x;
    int tid = threadIdx.x;
    const float* xr = x + (size_t)row * Dn;
    float v[4];
    float s = 0.f;
#pragma unroll
    for (int i = 0; i < 4; i++) { v[i] = xr[tid + i * 256]; s += v[i]; }
    __shared__ float red[256];
    red[tid] = s; __syncthreads();
    for (int o = 128; o > 0; o >>= 1) { if (tid < o) red[tid] += red[tid + o]; __syncthreads(); }
    float mean = red[0] * (1.f / Dn);
    __syncthreads();
    float sq = 0.f;
#pragma unroll
    for (int i = 0; i < 4; i++) { float d = v[i] - mean; sq += d * d; }
    red[tid] = sq; __syncthreads();
    for (int o = 128; o > 0; o >>= 1) { if (tid < o) red[tid] += red[tid + o]; __syncthreads(); }
    float rstd = rsqrtf(red[0] * (1.f / Dn) + EPSf);
    float* orow = out + (size_t)row * Dn;
#pragma unroll
    for (int i = 0; i < 4; i++) {
        int c = tid + i * 256;
        orow[c] = (v[i] - mean) * rstd * g[c] + b[c];
    }
}

// ---------------- fp32 tiled GEMM: C = A[MxK] @ W[KxN] + bias, epilogue ----
// EPI: 0 = none, 1 = exact GELU, 2 = residual add
template<int EPI>
__global__ __launch_bounds__(256) void gemm_kernel(const float* __restrict__ A,
                                                   const float* __restrict__ W,
                                                   const float* __restrict__ bias,
                                                   const float* __restrict__ resid,
                                                   float* __restrict__ C,
                                                   int M, int N, int K) {
    const int BM = 64, BN = 64, BK = 16;
    __shared__ float As[BK][BM + 1];
    __shared__ float Ws[BK][BN];
    int tx = threadIdx.x, ty = threadIdx.y;
    int tid = ty * 16 + tx;
    int row0 = blockIdx.y * BM, col0 = blockIdx.x * BN;
    float acc[4][4] = {};
    for (int k0 = 0; k0 < K; k0 += BK) {
#pragma unroll
        for (int i = 0; i < 4; i++) {          // A tile 64x16
            int idx = i * 256 + tid;
            int ar = idx >> 4, ac = idx & 15;
            int grow = row0 + ar;
            As[ac][ar] = (grow < M) ? A[(size_t)grow * K + k0 + ac] : 0.f;
        }
#pragma unroll
        for (int i = 0; i < 4; i++) {          // W tile 16x64
            int idx = i * 256 + tid;
            int wr = idx >> 6, wc = idx & 63;
            Ws[wr][wc] = W[(size_t)(k0 + wr) * N + col0 + wc];
        }
        __syncthreads();
#pragma unroll
        for (int kk = 0; kk < BK; kk++) {
            float a[4], w[4];
#pragma unroll
            for (int i = 0; i < 4; i++) a[i] = As[kk][ty * 4 + i];
#pragma unroll
            for (int j = 0; j < 4; j++) w[j] = Ws[kk][tx * 4 + j];
#pragma unroll
            for (int i = 0; i < 4; i++)
#pragma unroll
                for (int j = 0; j < 4; j++)
                    acc[i][j] += a[i] * w[j];
        }
        __syncthreads();
    }
#pragma unroll
    for (int i = 0; i < 4; i++) {
        int grow = row0 + ty * 4 + i;
        if (grow >= M) continue;
#pragma unroll
        for (int j = 0; j < 4; j++) {
            int gcol = col0 + tx * 4 + j;
            float r = acc[i][j] + bias[gcol];
            if (EPI == 1) r = 0.5f * r * (1.f + erff(r * 0.70710678118654752f));
            if (EPI == 2) r += resid[(size_t)grow * N + gcol];
            C[(size_t)grow * N + gcol] = r;
        }
    }
}

// ---------------- flash attention: block = (q-tile of 64, b*h) -------------
// 256 threads as 16x16; each thread owns a 4x4 microtile.
// KT is K stored transposed in LDS ([d][krow]) so both GEMMs read float4.
__global__ __launch_bounds__(256) void flash_kernel(const float* __restrict__ Q,
                                                    const float* __restrict__ K,
                                                    const float* __restrict__ V,
                                                    float* __restrict__ O) {
    __shared__ float Qs[64][68];
    __shared__ float KT[64][68];   // [d][krow]
    __shared__ float Vs[64][68];   // [krow][d]
    __shared__ float Ps[64][68];   // [qrow][krow]

    int qt = blockIdx.x;           // 0..9
    int bh = blockIdx.y;           // 0..255
    int b = bh >> 4, h = bh & 15;
    int tid = threadIdx.x;
    int tx = tid & 15, ty = tid >> 4;
    size_t base = ((size_t)b * Sn) * Dn + (size_t)h * DHn;
    int q0 = qt * 64;

    // load Q tile (pre-scaled by 1/sqrt(DH) = 0.125)
    {
        int r = tid >> 4;            // 0..15
        int c = (tid & 15) * 4;
#pragma unroll
        for (int i = 0; i < 4; i++) {
            int rr = r + i * 16;
            int gq = q0 + rr;
            float4 val = make_float4(0.f, 0.f, 0.f, 0.f);
            if (gq < Sn) val = *(const float4*)&Q[base + (size_t)gq * Dn + c];
            Qs[rr][c + 0] = val.x * 0.125f;
            Qs[rr][c + 1] = val.y * 0.125f;
            Qs[rr][c + 2] = val.z * 0.125f;
            Qs[rr][c + 3] = val.w * 0.125f;
        }
    }

    float m_r[4], l_r[4], acc[4][4];
#pragma unroll
    for (int i = 0; i < 4; i++) {
        m_r[i] = -1e30f; l_r[i] = 0.f;
#pragma unroll
        for (int j = 0; j < 4; j++) acc[i][j] = 0.f;
    }

    for (int kt = 0; kt < 10; kt++) {
        int kb = kt * 64;
        // load K (transposed) and V tiles; zero-fill invalid rows
        {
            int r = tid >> 4;
            int c = (tid & 15) * 4;
#pragma unroll
            for (int i = 0; i < 4; i++) {
                int rr = r + i * 16;
                int gk = kb + rr;
                float4 kv = make_float4(0.f, 0.f, 0.f, 0.f);
                float4 vv = make_float4(0.f, 0.f, 0.f, 0.f);
                if (gk < Sn) {
                    kv = *(const float4*)&K[base + (size_t)gk * Dn + c];
                    vv = *(const float4*)&V[base + (size_t)gk * Dn + c];
                }
                KT[c + 0][rr] = kv.x;
                KT[c + 1][rr] = kv.y;
                KT[c + 2][rr] = kv.z;
                KT[c + 3][rr] = kv.w;
                Vs[rr][c + 0] = vv.x;
                Vs[rr][c + 1] = vv.y;
                Vs[rr][c + 2] = vv.z;
                Vs[rr][c + 3] = vv.w;
            }
        }
        __syncthreads();

        // S = Qs @ K^T  (s[i][j], qrow=ty*4+i, kcol=tx*4+j)
        float s[4][4] = {};
#pragma unroll
        for (int kk4 = 0; kk4 < 16; kk4++) {
            float4 a4[4], b4[4];
#pragma unroll
            for (int i = 0; i < 4; i++) a4[i] = *(const float4*)&Qs[ty * 4 + i][kk4 * 4];
#pragma unroll
            for (int q = 0; q < 4; q++) b4[q] = *(const float4*)&KT[kk4 * 4 + q][tx * 4];
#pragma unroll
            for (int i = 0; i < 4; i++) {
                float av[4] = {a4[i].x, a4[i].y, a4[i].z, a4[i].w};
#pragma unroll
                for (int q = 0; q < 4; q++) {
                    s[i][0] += av[q] * b4[q].x;
                    s[i][1] += av[q] * b4[q].y;
                    s[i][2] += av[q] * b4[q].z;
                    s[i][3] += av[q] * b4[q].w;
                }
            }
        }

        // online softmax update (row stats duplicated across the 16-lane tx group)
        bool cvalid[4];
#pragma unroll
        for (int j = 0; j < 4; j++) cvalid[j] = (kb + tx * 4 + j) < Sn;
#pragma unroll
        for (int i = 0; i < 4; i++) {
            float lmax = -1e30f;
#pragma unroll
            for (int j = 0; j < 4; j++) if (cvalid[j]) lmax = fmaxf(lmax, s[i][j]);
            lmax = fmaxf(lmax, __shfl_xor(lmax, 1));
            lmax = fmaxf(lmax, __shfl_xor(lmax, 2));
            lmax = fmaxf(lmax, __shfl_xor(lmax, 4));
            lmax = fmaxf(lmax, __shfl_xor(lmax, 8));
            float mnew = fmaxf(m_r[i], lmax);
            float scale = __expf(m_r[i] - mnew);
            float rsum = 0.f;
#pragma unroll
            for (int j = 0; j < 4; j++) {
                float p = cvalid[j] ? __expf(s[i][j] - mnew) : 0.f;
                s[i][j] = p;
                rsum += p;
            }
            rsum += __shfl_xor(rsum, 1);
            rsum += __shfl_xor(rsum, 2);
            rsum += __shfl_xor(rsum, 4);
            rsum += __shfl_xor(rsum, 8);
            l_r[i] = l_r[i] * scale + rsum;
            m_r[i] = mnew;
#pragma unroll
            for (int j = 0; j < 4; j++) acc[i][j] *= scale;
        }

        // write P tile
#pragma unroll
        for (int i = 0; i < 4; i++)
#pragma unroll
            for (int j = 0; j < 4; j++)
                Ps[ty * 4 + i][tx * 4 + j] = s[i][j];
        __syncthreads();

        // acc += P @ V
#pragma unroll
        for (int kk4 = 0; kk4 < 16; kk4++) {
            float4 a4[4], b4[4];
#pragma unroll
            for (int i = 0; i < 4; i++) a4[i] = *(const float4*)&Ps[ty * 4 + i][kk4 * 4];
#pragma unroll
            for (int q = 0; q < 4; q++) b4[q] = *(const float4*)&Vs[kk4 * 4 + q][tx * 4];
#pragma unroll
            for (int i = 0; i < 4; i++) {
                float av[4] = {a4[i].x, a4[i].y, a4[i].z, a4[i].w};
#pragma unroll
                for (int q = 0; q < 4; q++) {
                    acc[i][0] += av[q] * b4[q].x;
                    acc[i][1] += av[q] * b4[q].y;
                    acc[i][2] += av[q] * b4[q].z;
                    acc[i][3] += av[q] * b4[q].w;
                }
            }
        }
        __syncthreads();   // before next tile overwrites KT/Vs/Ps
    }

    // write O rows
#pragma unroll
    for (int i = 0; i < 4; i++) {
        int gq = q0 + ty * 4 + i;
        if (gq >= Sn) continue;
        float inv = 1.f / l_r[i];
#pragma unroll
        for (int j = 0; j < 4; j++)
            O[base + (size_t)gq * Dn + tx * 4 + j] = acc[i][j] * inv;
    }
}

extern "C" void kernel_launch(void* const* d_in, const int* in_sizes, int n_in,
                              void* d_out, int out_size, void* d_ws, size_t ws_size,
                              hipStream_t stream) {
    const float* x    = (const float*)d_in[0];
    const float* ln1g = (const float*)d_in[1];
    const float* ln1b = (const float*)d_in[2];
    const float* wq   = (const float*)d_in[3];
    const float* bq   = (const float*)d_in[4];
    const float* wk   = (const float*)d_in[5];
    const float* bk   = (const float*)d_in[6];
    const float* wv   = (const float*)d_in[7];
    const float* bv   = (const float*)d_in[8];
    const float* wo   = (const float*)d_in[9];
    const float* bo   = (const float*)d_in[10];
    const float* ln2g = (const float*)d_in[11];
    const float* ln2b = (const float*)d_in[12];
    const float* w1   = (const float*)d_in[13];
    const float* b1   = (const float*)d_in[14];
    const float* w2   = (const float*)d_in[15];
    const float* b2   = (const float*)d_in[16];
    float* out = (float*)d_out;

    const size_t SZ_ROWD = (size_t)NROW * Dn * sizeof(float);   // 37,814,272
    char* ws = (char*)d_ws;
    float* qbuf  = (float*)(ws);                    // [0, 37.8MB)
    float* kbuf  = (float*)(ws + SZ_ROWD);          // [37.8, 75.6)
    float* vbuf  = (float*)(ws + 2 * SZ_ROWD);      // [75.6, 113.4)
    float* hmid  = (float*)(ws);                    // [0, 151.3) reuses q/k/v
    float* xnbuf = (float*)(ws + 4 * SZ_ROWD);      // [151.3, 189.1)  (xn, then xn2)
    float* ctx   = (float*)(ws + 5 * SZ_ROWD);      // [189.1, 226.9)
    float* x1    = (float*)(ws + 6 * SZ_ROWD);      // [226.9, 264.7)

    dim3 blk2(16, 16);
    dim3 gD(Dn / 64, (NROW + 63) / 64);
    dim3 gF(Fn / 64, (NROW + 63) / 64);

    // attention sublayer
    ln_kernel<<<NROW, 256, 0, stream>>>(x, ln1g, ln1b, xnbuf);
    gemm_kernel<0><<<gD, blk2, 0, stream>>>(xnbuf, wq, bq, nullptr, qbuf, NROW, Dn, Dn);
    gemm_kernel<0><<<gD, blk2, 0, stream>>>(xnbuf, wk, bk, nullptr, kbuf, NROW, Dn, Dn);
    gemm_kernel<0><<<gD, blk2, 0, stream>>>(xnbuf, wv, bv, nullptr, vbuf, NROW, Dn, Dn);
    flash_kernel<<<dim3(10, Bn * Hn), 256, 0, stream>>>(qbuf, kbuf, vbuf, ctx);
    gemm_kernel<2><<<gD, blk2, 0, stream>>>(ctx, wo, bo, x, x1, NROW, Dn, Dn);
    // MLP sublayer
    ln_kernel<<<NROW, 256, 0, stream>>>(x1, ln2g, ln2b, xnbuf);
    gemm_kernel<1><<<gF, blk2, 0, stream>>>(xnbuf, w1, b1, nullptr, hmid, NROW, Fn, Dn);
    gemm_kernel<2><<<gD, blk2, 0, stream>>>(hmid, w2, b2, x1, out, NROW, Dn, Fn);
}